// Round 11
// baseline (3057.228 us; speedup 1.0000x reference)
//
#include <hip/hip_runtime.h>
#include <math.h>

#define T_TOTAL   1000
#define BATCH     256
#define NH        256
#define NIN       85

static constexpr float SIGMA_C = 0.15811388300841897f;  // sqrt(2/0.2)*0.05
static constexpr float ALPHA_C = 0.2f;

using half4   = __attribute__((ext_vector_type(4))) _Float16;
using half8   = __attribute__((ext_vector_type(8))) _Float16;
using f32x4   = __attribute__((ext_vector_type(4))) float;

// workspace layout (ushort units)
#define GXEG_US   ((size_t)(T_TOTAL+1)*16*4*64*32)  // f16 gate preacts [t][R][w4][lane][32] = 262MB
#define GXEE_US   ((size_t)(T_TOTAL+1)*16*4*64*16)  // f16 E tiles      [t][R][w4][lane][16] = 131MB
#define WPACK_US  (4u*3u*4u*8u*64u*8u)              // recurrent-weight B-fragments (f16 bits)
#define WXPACK_US (48u*3u*64u*8u)                   // x-weight B-fragments (K padded 85->96)

__device__ __forceinline__ unsigned short f2h(float f){
  _Float16 h = (_Float16)f;
  return __builtin_bit_cast(unsigned short, h);
}

// ---------------- k0: pack weights into MFMA B-fragment order (f16) ----------------
// wpack[w4(4)][kind(3: r,u,c)][j(4)][kt(8)][lane(64)][j8(8)]
//   tau = 4*w4 + j; value = W[k = kt*32 + (l>>4)*8 + j8][col = 16*tau + (l&15)]
__global__ void k0_pack(const float* __restrict__ gk, const float* __restrict__ ck,
                        unsigned short* __restrict__ wpack, unsigned short* __restrict__ wxpack){
  int tid = blockIdx.x*256 + threadIdx.x;
  if (tid < (int)WPACK_US) {
    int j8 = tid & 7, l = (tid >> 3) & 63, kt = (tid >> 9) & 7, rest = tid >> 12;
    int j = rest & 3, kind = (rest >> 2) % 3, w4 = (rest >> 2) / 3;
    int lrow = l & 15, lquad = l >> 4;
    int k = kt*32 + lquad*8 + j8;           // hidden index 0..255
    int tau = 4*w4 + j;                     // n-tile 0..15
    float v;
    if (kind == 0)      v = gk[(size_t)(85 + k)*512 + 16*tau + lrow];
    else if (kind == 1) v = gk[(size_t)(85 + k)*512 + 256 + 16*tau + lrow];
    else                v = ck[(size_t)(85 + k)*256 + 16*tau + lrow];
    wpack[tid] = f2h(v);
  } else if (tid < (int)(WPACK_US + WXPACK_US)) {
    int f = tid - (int)WPACK_US;
    int j = f & 7, l = (f >> 3) & 63, r = f >> 9;   // r = tau*3 + kt
    int kt = r % 3, tau = r / 3;
    int lrow = l & 15, lquad = l >> 4;
    int k = kt*32 + lquad*8 + j;            // x index, pad >=85 -> 0
    float v = 0.0f;
    if (k < NIN) {
      if (tau < 32) v = gk[(size_t)k*512 + 16*tau + lrow];
      else          v = ck[(size_t)k*256 + 16*(tau-32) + lrow];
    }
    wxpack[f] = f2h(v);
  }
}

// ---------------- k1: gxe precompute, ONE dispatch over all T ----------------
// gates (tau<32): kind=tau>>4 (0=r,1=u), w4=(tau&15)>>2, pos=tau&3
//   -> f16 gxeG[t][R][w4][lane][kind*16 + pos*4 + i]
// E (tau>=32, e=tau-32): w4=e>>2, pos=e&3 -> f16 gxeE[t][R][w4][lane][pos*4 + i]
__global__ __launch_bounds__(256) void k1_gxe(const float* __restrict__ x, const float* __restrict__ nz,
                       const float* __restrict__ gb, const float* __restrict__ cb,
                       const unsigned short* __restrict__ wxpack,
                       unsigned short* __restrict__ gxeG, unsigned short* __restrict__ gxeE){
  int R  = blockIdx.x;
  int t  = blockIdx.y;
  int tid = threadIdx.x;
  __shared__ _Float16 xA[16][104];           // 96 K (padded) + 8 pad
  {
    int r = tid >> 4, c0 = tid & 15;
    const float* xrow = x + ((size_t)t*BATCH + 16*R + r)*NIN;
    for (int c = c0; c < 96; c += 16)
      xA[r][c] = (_Float16)(c < NIN ? xrow[c] : 0.0f);
  }
  __syncthreads();
  int l = tid & 63, wv = tid >> 6;
  int lrow = l & 15, lquad = l >> 4;
  const half8* xA8 = (const half8*)xA;       // row stride 104 f16 = 13 half8
  half8 afr[3];
  #pragma unroll
  for (int kt = 0; kt < 3; ++kt)
    afr[kt] = xA8[lrow*13 + kt*4 + lquad];
  const half8* wx8 = (const half8*)wxpack;
  for (int u = 0; u < 12; ++u) {
    int tau = wv + 4*u;                      // balanced: each wave gets 4 cand tiles
    f32x4 acc;
    if (tau < 32) {
      float b = gb[16*tau + lrow];
      acc = (f32x4){b, b, b, b};
    } else {
      int nc = 16*(tau-32) + lrow;
      float b = cb[nc];
      #pragma unroll
      for (int i = 0; i < 4; ++i)
        acc[i] = fmaf(SIGMA_C, nz[((size_t)t*BATCH + 16*R + lquad*4 + i)*NH + nc], b);
    }
    #pragma unroll
    for (int kt = 0; kt < 3; ++kt)
      acc = __builtin_amdgcn_mfma_f32_16x16x32_f16(afr[kt], wx8[((size_t)tau*3 + kt)*64 + l], acc, 0, 0, 0);
    half4 o = {(_Float16)acc[0], (_Float16)acc[1], (_Float16)acc[2], (_Float16)acc[3]};
    if (tau < 32) {
      int kind = tau >> 4, w4 = (tau & 15) >> 2, pos = tau & 3;
      *(half4*)(gxeG + ((((size_t)t*16 + R)*4 + w4)*64 + (size_t)l)*32 + kind*16 + pos*4) = o;
    } else {
      int e = tau - 32, w4 = e >> 2, pos = e & 3;
      *(half4*)(gxeE + ((((size_t)t*16 + R)*4 + w4)*64 + (size_t)l)*16 + pos*4) = o;
    }
  }
}

// ---------------- k2: ONE persistent recurrent scan over all 1000 steps ----------------
// 16 WGs x 4 waves (256 thr, launch_bounds(256,1) => 1 wave/SIMD => 512-reg unified budget).
// WG R owns rows [16R,16R+16); wave w owns cols [64w,64w+64) (taus 4w..4w+3 per kind).
// RATIONALE (R10 post-mortem): 8-wave is infeasible (192 weights + ~90 working > 256/wave
// cap => forced per-step spills). 4-wave fits: 384 weights + ~110 working < 512, with
// u/c tiles (256 regs) PINNED to AGPR and r tiles + working set in arch (<256). Plain
// MFMA intrinsics (compiler hazards). A-fragment LDS reads halve vs 8-wave.
// cand = cx + (r .* h) @ Wc_h + sigma*n. Sync: 2x (lgkmcnt(0); s_barrier) per step;
// out stores never drained in-loop; gate/E streams HBM->VGPR double-buffered.
__global__ __launch_bounds__(256, 1) void k2_rec(const float* __restrict__ hin,
                       const unsigned short* __restrict__ wpack,
                       const unsigned short* __restrict__ gG,
                       const unsigned short* __restrict__ gE,
                       float* __restrict__ out){
  int R = blockIdx.x;
  int tid = threadIdx.x;
  int l = tid & 63, w = tid >> 6;
  int lrow = l & 15, lquad = l >> 4;

  __shared__ _Float16 hA[16][264];           // h f16  [row][n], stride 264
  __shared__ _Float16 rhA[16][264];          // r.*h f16, same layout

  { // init hA (256 threads x 16 elems)
    int r = tid >> 4, c0 = (tid & 15)*16;
    const float* hrow = hin + ((size_t)(16*R + r))*NH + c0;
    #pragma unroll
    for (int i = 0; i < 16; ++i)
      hA[r][c0+i] = (_Float16)hrow[i];
  }
  float hreg[4][4];                          // h f32, lane-private (rows lquad*4+i, cols 64w+16j+lrow)
  #pragma unroll
  for (int j = 0; j < 4; ++j)
    #pragma unroll
    for (int i = 0; i < 4; ++i)
      hreg[j][i] = hin[(size_t)(16*R + lquad*4 + i)*NH + 64*w + 16*j + lrow];

  // resident weight fragments: r,u,c x 4 taus x 8 kt = 384 regs.
  // u,c (256 regs) pinned to AGPR; r (128) + working set stay arch.
  half8 wr[4][8], wu[4][8], wc[4][8];
  const half8* wp8 = (const half8*)wpack;
  #pragma unroll
  for (int j = 0; j < 4; ++j)
    #pragma unroll
    for (int kt = 0; kt < 8; ++kt){
      wr[j][kt] = wp8[(((w*3 + 0)*4 + j)*8 + kt)*64 + l];
      wu[j][kt] = wp8[(((w*3 + 1)*4 + j)*8 + kt)*64 + l];
      wc[j][kt] = wp8[(((w*3 + 2)*4 + j)*8 + kt)*64 + l];
    }
  #pragma unroll
  for (int j = 0; j < 4; ++j)
    #pragma unroll
    for (int kt = 0; kt < 8; ++kt){
      asm volatile("" : "+a"(wu[j][kt]));    // pin home to AGPR (one-time copy)
      asm volatile("" : "+a"(wc[j][kt]));
    }

  // gate / E streams: per-lane 64B gates + 32B E per step, f16
  const half8* gg  = (const half8*)gG + (((size_t)R*4 + w)*64 + (size_t)l)*4;
  const size_t gstep = (size_t)16*4*64*4;    // half8 units per time step
  const half8* gep = (const half8*)gE + (((size_t)R*4 + w)*64 + (size_t)l)*2;
  const size_t estep = (size_t)16*4*64*2;
  half8 g0 = gg[0], g1 = gg[1], g2 = gg[2], g3 = gg[3];  gg += gstep;  // r p0-3 | u p0-3
  half8 e0 = gep[0], e1 = gep[1];                        gep += estep; // E p0-3
  __syncthreads();

  const half8* hA8  = (const half8*)hA;      // row stride 33 half8
  const half8* rhA8 = (const half8*)rhA;
  float* outp = out + ((size_t)(16*R + lquad*4))*NH + 64*w + lrow;

  for (int t = 0; t < T_TOTAL; ++t) {
    // acc init from prefetched gates (lane-private, no LDS)
    f32x4 accr[4], accu[4];
    #pragma unroll
    for (int j = 0; j < 4; ++j)
      #pragma unroll
      for (int i = 0; i < 4; ++i){
        accr[j][i] = (float)((j < 2 ? g0 : g1)[(j&1)*4 + i]);
        accu[j][i] = (float)((j < 2 ? g2 : g3)[(j&1)*4 + i]);
      }
    // prefetch gates(t+1) (slack slab at t=999); full step covers HBM latency
    g0 = gg[0]; g1 = gg[1]; g2 = gg[2]; g3 = gg[3]; gg += gstep;
    // phase A: h @ Wg_h  (r tiles from arch, u tiles from AGPR)
    #pragma unroll
    for (int kt = 0; kt < 8; ++kt){
      half8 af = hA8[lrow*33 + kt*4 + lquad];
      #pragma unroll
      for (int j = 0; j < 4; ++j){
        accr[j] = __builtin_amdgcn_mfma_f32_16x16x32_f16(af, wr[j][kt], accr[j], 0, 0, 0);
        accu[j] = __builtin_amdgcn_mfma_f32_16x16x32_f16(af, wu[j][kt], accu[j], 0, 0, 0);
      }
    }
    // ew1: u-gates -> packed f16 aug; r-gates -> rhA
    half4 haug[4];
    #pragma unroll
    for (int j = 0; j < 4; ++j)
      #pragma unroll
      for (int i = 0; i < 4; ++i){
        float eu = __expf(-accu[j][i]);
        haug[j][i] = (_Float16)(ALPHA_C * __builtin_amdgcn_rcpf(1.0f + eu));
      }
    #pragma unroll
    for (int j = 0; j < 4; ++j){
      int ncol = 64*w + 16*j + lrow;
      #pragma unroll
      for (int i = 0; i < 4; ++i){
        float er = __expf(-accr[j][i]);
        float rg = __builtin_amdgcn_rcpf(1.0f + er);
        rhA[lquad*4+i][ncol] = (_Float16)(rg * hreg[j][i]);
      }
    }
    asm volatile("s_waitcnt lgkmcnt(0)\n\ts_barrier" ::: "memory");  // rhA visible
    // phase B: (r.*h) @ Wc_h  (c tiles from AGPR)
    f32x4 accB[4];
    #pragma unroll
    for (int j = 0; j < 4; ++j) accB[j] = (f32x4){0.f,0.f,0.f,0.f};
    #pragma unroll
    for (int kt = 0; kt < 8; ++kt){
      half8 af = rhA8[lrow*33 + kt*4 + lquad];
      #pragma unroll
      for (int j = 0; j < 4; ++j)
        accB[j] = __builtin_amdgcn_mfma_f32_16x16x32_f16(af, wc[j][kt], accB[j], 0, 0, 0);
    }
    // ew2: cand -> tanh -> leaky update; publish new h; 16 out stores (never drained)
    #pragma unroll
    for (int j = 0; j < 4; ++j){
      int ncol = 64*w + 16*j + lrow;
      #pragma unroll
      for (int i = 0; i < 4; ++i){
        float ev = (float)((j < 2 ? e0 : e1)[(j&1)*4 + i]);
        float cand = accB[j][i] + ev;
        float e2 = __expf(2.0f*cand);
        float c  = (e2 - 1.0f)*__builtin_amdgcn_rcpf(e2 + 1.0f);
        float hold = hreg[j][i];
        float hnew = fmaf((float)haug[j][i], c - hold, hold);
        hreg[j][i] = hnew;
        hA[lquad*4+i][ncol] = (_Float16)hnew;
        outp[(size_t)i*NH + (size_t)j*16] = hnew;
      }
    }
    outp += (size_t)BATCH*NH;
    // prefetch E(t+1) after last use
    e0 = gep[0]; e1 = gep[1]; gep += estep;
    asm volatile("s_waitcnt lgkmcnt(0)\n\ts_barrier" ::: "memory");  // hA visible
  }
}

extern "C" void kernel_launch(void* const* d_in, const int* in_sizes, int n_in,
                              void* d_out, int out_size, void* d_ws, size_t ws_size,
                              hipStream_t stream) {
  (void)in_sizes; (void)n_in; (void)out_size; (void)ws_size;
  const float* x  = (const float*)d_in[0];
  const float* h0 = (const float*)d_in[1];
  const float* gk = (const float*)d_in[2];
  const float* gb = (const float*)d_in[3];
  const float* ck = (const float*)d_in[4];
  const float* cb = (const float*)d_in[5];
  const float* nz = (const float*)d_in[6];
  float* out = (float*)d_out;

  unsigned short* gxeG   = (unsigned short*)d_ws;           // 262MB f16 gates
  unsigned short* gxeE   = gxeG + GXEG_US;                  // 131MB f16 E
  unsigned short* wpack  = gxeE + GXEE_US;
  unsigned short* wxpack = wpack + WPACK_US;

  k0_pack<<<1056, 256, 0, stream>>>(gk, ck, wpack, wxpack);
  k1_gxe<<<dim3(16, T_TOTAL), 256, 0, stream>>>(x, nz, gb, cb, wxpack, gxeG, gxeE);
  k2_rec<<<16, 256, 0, stream>>>(h0, wpack, gxeG, gxeE, out);
}

// Round 12
// 2268.825 us; speedup vs baseline: 1.3475x; 1.3475x over previous
//
#include <hip/hip_runtime.h>
#include <math.h>

#define T_TOTAL   1000
#define BATCH     256
#define NH        256
#define NIN       85

static constexpr float SIGMA_C = 0.15811388300841897f;  // sqrt(2/0.2)*0.05
static constexpr float ALPHA_C = 0.2f;

using half2v  = __attribute__((ext_vector_type(2))) _Float16;
using half4   = __attribute__((ext_vector_type(4))) _Float16;
using half8   = __attribute__((ext_vector_type(8))) _Float16;
using f32x4   = __attribute__((ext_vector_type(4))) float;

// workspace layout (ushort units)
#define GXEG_US   ((size_t)(T_TOTAL+1)*16*8*64*16)  // f16 gate preacts [t][R][w][lane][16] = 262MB
#define GXEE_US   ((size_t)(T_TOTAL+1)*16*8*64*8)   // f16 E tiles      [t][R][w][lane][8]  = 131MB
#define WPACK_US  (8u*6u*8u*64u*8u)                 // recurrent-weight B-fragments (f16 bits)
#define WXPACK_US (48u*3u*64u*8u)                   // x-weight B-fragments (K padded 85->96)

// k-permutation: h columns are stored at s = w*32 + 2*lrow + p for real col
// c = 32w + 16p + lrow. MFMA contraction is invariant when wpack's K rows are
// permuted identically (k0 does). Purpose: each lane's (p=0,1) ew outputs are
// ADJACENT in LDS -> packed ds_write_b32 (halves DS write ops).
__device__ __forceinline__ int kperm(int s){
  return 32*(s >> 5) + 16*(s & 1) + ((s & 31) >> 1);
}

__device__ __forceinline__ unsigned short f2h(float f){
  _Float16 h = (_Float16)f;
  return __builtin_bit_cast(unsigned short, h);
}

// ---------------- k0: pack weights into MFMA B-fragment order (f16) ----------------
// wpack[w(8)][tile(6: r0,r1,u0,u1,c0,c1)][kt(8)][lane(64)][j(8)]
//   tau = 2w + (tile&1); storage k s = kt*32 + (l>>4)*8 + j -> real k = kperm(s)
__global__ void k0_pack(const float* __restrict__ gk, const float* __restrict__ ck,
                        unsigned short* __restrict__ wpack, unsigned short* __restrict__ wxpack){
  int tid = blockIdx.x*256 + threadIdx.x;
  if (tid < (int)WPACK_US) {
    int j = tid & 7, l = (tid >> 3) & 63, kt = (tid >> 9) & 7, wt = tid >> 12;
    int w = wt / 6, tile = wt - 6*w;
    int lrow = l & 15, lquad = l >> 4;
    int s = kt*32 + lquad*8 + j;            // storage k
    int k = kperm(s);                       // real hidden index 0..255
    int tau = 2*w + (tile & 1);             // n-tile 0..15
    int kind = tile >> 1;                   // 0=r, 1=u, 2=c
    float v;
    if (kind == 0)      v = gk[(size_t)(85 + k)*512 + 16*tau + lrow];
    else if (kind == 1) v = gk[(size_t)(85 + k)*512 + 256 + 16*tau + lrow];
    else                v = ck[(size_t)(85 + k)*256 + 16*tau + lrow];
    wpack[tid] = f2h(v);
  } else if (tid < (int)(WPACK_US + WXPACK_US)) {
    int f = tid - (int)WPACK_US;
    int j = f & 7, l = (f >> 3) & 63, r = f >> 9;   // r = tau*3 + kt
    int kt = r % 3, tau = r / 3;
    int lrow = l & 15, lquad = l >> 4;
    int k = kt*32 + lquad*8 + j;            // x index (NOT permuted), pad >=85 -> 0
    float v = 0.0f;
    if (k < NIN) {
      if (tau < 32) v = gk[(size_t)k*512 + 16*tau + lrow];
      else          v = ck[(size_t)k*256 + 16*(tau-32) + lrow];
    }
    wxpack[f] = f2h(v);
  }
}

// ---------------- k1: gxe precompute, ONE dispatch over all T (unchanged from R10) ----------------
__global__ __launch_bounds__(256) void k1_gxe(const float* __restrict__ x, const float* __restrict__ nz,
                       const float* __restrict__ gb, const float* __restrict__ cb,
                       const unsigned short* __restrict__ wxpack,
                       unsigned short* __restrict__ gxeG, unsigned short* __restrict__ gxeE){
  int R  = blockIdx.x;
  int t  = blockIdx.y;
  int tid = threadIdx.x;
  __shared__ _Float16 xA[16][104];           // 96 K (padded) + 8 pad
  {
    int r = tid >> 4, c0 = tid & 15;
    const float* xrow = x + ((size_t)t*BATCH + 16*R + r)*NIN;
    for (int c = c0; c < 96; c += 16)
      xA[r][c] = (_Float16)(c < NIN ? xrow[c] : 0.0f);
  }
  __syncthreads();
  int l = tid & 63, wv = tid >> 6;
  int lrow = l & 15, lquad = l >> 4;
  const half8* xA8 = (const half8*)xA;       // row stride 104 f16 = 13 half8
  half8 afr[3];
  #pragma unroll
  for (int kt = 0; kt < 3; ++kt)
    afr[kt] = xA8[lrow*13 + kt*4 + lquad];
  const half8* wx8 = (const half8*)wxpack;
  for (int u = 0; u < 12; ++u) {
    int tau = wv + 4*u;                      // balanced: each wave gets 4 cand tiles
    f32x4 acc;
    if (tau < 32) {
      float b = gb[16*tau + lrow];
      acc = (f32x4){b, b, b, b};
    } else {
      int nc = 16*(tau-32) + lrow;
      float b = cb[nc];
      #pragma unroll
      for (int i = 0; i < 4; ++i)
        acc[i] = fmaf(SIGMA_C, nz[((size_t)t*BATCH + 16*R + lquad*4 + i)*NH + nc], b);
    }
    #pragma unroll
    for (int kt = 0; kt < 3; ++kt)
      acc = __builtin_amdgcn_mfma_f32_16x16x32_f16(afr[kt], wx8[((size_t)tau*3 + kt)*64 + l], acc, 0, 0, 0);
    half4 o = {(_Float16)acc[0], (_Float16)acc[1], (_Float16)acc[2], (_Float16)acc[3]};
    if (tau < 32) {
      int kind = tau >> 4, w2 = (tau & 15) >> 1, p = tau & 1;
      *(half4*)(gxeG + ((((size_t)t*16 + R)*8 + w2)*64 + (size_t)l)*16 + kind*8 + p*4) = o;
    } else {
      int e = tau - 32, w2 = e >> 1, p = e & 1;
      *(half4*)(gxeE + ((((size_t)t*16 + R)*8 + w2)*64 + (size_t)l)*8 + p*4) = o;
    }
  }
}

// ---------------- k2: ONE persistent recurrent scan over all 1000 steps ----------------
// 16 WGs x 8 waves (2 waves/SIMD). WG R owns rows [16R,16R+16); wave w owns cols [32w,32w+32).
// cand = cx + (r .* h) @ Wc_h + sigma*n  (r applied BEFORE the matmul).
// R12 changes vs R10 (champion): (1) k-permuted h/rh storage -> all LDS publishes are
// packed ds_write_b32 (16 -> 8 write ops/lane/step); (2) ew1 split: r+rhA-write before
// the barrier, u transcendentals after it (overlap with phase-B issue); (3) tanh via
// 1 - 2/(e2+1). Gate/E streams stay HBM->VGPR f16, double-buffered. 2 barriers/step.
__global__ __launch_bounds__(512, 2) void k2_rec(const float* __restrict__ hin,
                       const unsigned short* __restrict__ wpack,
                       const unsigned short* __restrict__ gG,
                       const unsigned short* __restrict__ gE,
                       float* __restrict__ out){
  int R = blockIdx.x;
  int tid = threadIdx.x;
  int l = tid & 63, w = tid >> 6;
  int lrow = l & 15, lquad = l >> 4;

  __shared__ _Float16 hA[16][264];           // h f16  [row][k-storage], stride 264
  __shared__ _Float16 rhA[16][264];          // r.*h f16, same layout

  { // init hA in permuted storage order
    int r = tid >> 5, s0 = (tid & 31)*8;
    const float* hrow = hin + ((size_t)(16*R + r))*NH;
    #pragma unroll
    for (int m = 0; m < 8; ++m){
      int s = s0 + m;
      hA[r][s] = (_Float16)hrow[kperm(s)];
    }
  }
  float hreg[2][4];                          // h f32, lane-private (rows lquad*4+i, cols 32w+16p+lrow)
  #pragma unroll
  for (int p = 0; p < 2; ++p)
    #pragma unroll
    for (int i = 0; i < 4; ++i)
      hreg[p][i] = hin[(size_t)(16*R + lquad*4 + i)*NH + 32*w + 16*p + lrow];

  // resident weight fragments (192 regs; compiler splits arch/AGPR as it sees fit)
  half8 wf[6][8];
  const half8* wp8 = (const half8*)wpack;
  #pragma unroll
  for (int tile = 0; tile < 6; ++tile)
    #pragma unroll
    for (int kt = 0; kt < 8; ++kt)
      wf[tile][kt] = wp8[((w*6 + tile)*8 + kt)*64 + l];

  // gate / E streams: per-lane 32B (gates) + 16B (E) per step, f16
  const half8* gg  = (const half8*)gG + (((size_t)R*8 + w)*64 + (size_t)l)*2;
  const size_t gstepG = (size_t)16*8*64*2;   // half8 units per time step
  const half8* gep = (const half8*)gE + (((size_t)R*8 + w)*64 + (size_t)l);
  const size_t estep = (size_t)16*8*64;      // half8 units per time step

  half8 g0 = gg[0], g1 = gg[1];  gg += gstepG;   // gates(0): [r p0..p1 | u p0..p1]
  half8 eh = gep[0];             gep += estep;   // E(0)
  __syncthreads();

  const half8* hA8  = (const half8*)hA;      // row stride 33 half8
  const half8* rhA8 = (const half8*)rhA;
  // packed b32 publish pointers: half-index w*32 + 2*lrow in each row
  half2v* rhW = (half2v*)&rhA[0][w*32 + 2*lrow];   // row stride 132 half2
  half2v* hW  = (half2v*)&hA [0][w*32 + 2*lrow];
  float* outp = out + ((size_t)(16*R + lquad*4))*NH + 32*w + lrow;

  for (int t = 0; t < T_TOTAL; ++t) {
    // acc init from prefetched gates (lane-private, no LDS)
    f32x4 accr[2], accu[2];
    #pragma unroll
    for (int p = 0; p < 2; ++p)
      #pragma unroll
      for (int i = 0; i < 4; ++i){
        accr[p][i] = (float)g0[p*4 + i];
        accu[p][i] = (float)g1[p*4 + i];
      }
    // prefetch gates(t+1) (slack slab at t=999); ~full step covers HBM latency
    g0 = gg[0]; g1 = gg[1]; gg += gstepG;
    // phase A: h @ Wg_h  (tiles r0,r1,u0,u1)
    #pragma unroll
    for (int kt = 0; kt < 8; ++kt){
      half8 af = hA8[lrow*33 + kt*4 + lquad];
      #pragma unroll
      for (int p = 0; p < 2; ++p){
        accr[p] = __builtin_amdgcn_mfma_f32_16x16x32_f16(af, wf[p  ][kt], accr[p], 0, 0, 0);
        accu[p] = __builtin_amdgcn_mfma_f32_16x16x32_f16(af, wf[2+p][kt], accu[p], 0, 0, 0);
      }
    }
    // ew1a: r-gates -> packed rh publish (before barrier; shortest path to phase B)
    #pragma unroll
    for (int i = 0; i < 4; ++i){
      float rg0 = __builtin_amdgcn_rcpf(1.0f + __expf(-accr[0][i]));
      float rg1 = __builtin_amdgcn_rcpf(1.0f + __expf(-accr[1][i]));
      half2v pk = {(_Float16)(rg0 * hreg[0][i]), (_Float16)(rg1 * hreg[1][i])};
      rhW[(lquad*4 + i)*132] = pk;           // one ds_write_b32
    }
    asm volatile("s_waitcnt lgkmcnt(0)\n\ts_barrier" ::: "memory");  // rhA visible
    // ew1b: u-gates (overlaps with phase-B MFMA issue)
    half4 haug[2];
    #pragma unroll
    for (int p = 0; p < 2; ++p)
      #pragma unroll
      for (int i = 0; i < 4; ++i){
        float eu = __expf(-accu[p][i]);
        haug[p][i] = (_Float16)(ALPHA_C * __builtin_amdgcn_rcpf(1.0f + eu));
      }
    // phase B: (r.*h) @ Wc_h  (tiles c0,c1)
    f32x4 accB[2];
    accB[0] = (f32x4){0.f,0.f,0.f,0.f};
    accB[1] = (f32x4){0.f,0.f,0.f,0.f};
    #pragma unroll
    for (int kt = 0; kt < 8; ++kt){
      half8 af = rhA8[lrow*33 + kt*4 + lquad];
      #pragma unroll
      for (int p = 0; p < 2; ++p)
        accB[p] = __builtin_amdgcn_mfma_f32_16x16x32_f16(af, wf[4+p][kt], accB[p], 0, 0, 0);
    }
    // ew2: cand -> tanh -> leaky update; packed h publish; 8 out stores (never drained)
    #pragma unroll
    for (int i = 0; i < 4; ++i){
      float hn[2];
      #pragma unroll
      for (int p = 0; p < 2; ++p){
        float cand = accB[p][i] + (float)eh[p*4 + i];
        float e2 = __expf(2.0f*cand);
        float c  = fmaf(-2.0f, __builtin_amdgcn_rcpf(e2 + 1.0f), 1.0f);
        float hold = hreg[p][i];
        hn[p] = fmaf((float)haug[p][i], c - hold, hold);
        hreg[p][i] = hn[p];
      }
      half2v pk = {(_Float16)hn[0], (_Float16)hn[1]};
      hW[(lquad*4 + i)*132] = pk;            // one ds_write_b32
      outp[(size_t)i*NH]      = hn[0];
      outp[(size_t)i*NH + 16] = hn[1];
    }
    outp += (size_t)BATCH*NH;
    // prefetch E(t+1) after last use of eh
    eh = gep[0]; gep += estep;
    asm volatile("s_waitcnt lgkmcnt(0)\n\ts_barrier" ::: "memory");  // hA visible
  }
}

extern "C" void kernel_launch(void* const* d_in, const int* in_sizes, int n_in,
                              void* d_out, int out_size, void* d_ws, size_t ws_size,
                              hipStream_t stream) {
  (void)in_sizes; (void)n_in; (void)out_size; (void)ws_size;
  const float* x  = (const float*)d_in[0];
  const float* h0 = (const float*)d_in[1];
  const float* gk = (const float*)d_in[2];
  const float* gb = (const float*)d_in[3];
  const float* ck = (const float*)d_in[4];
  const float* cb = (const float*)d_in[5];
  const float* nz = (const float*)d_in[6];
  float* out = (float*)d_out;

  unsigned short* gxeG   = (unsigned short*)d_ws;           // 262MB f16 gates
  unsigned short* gxeE   = gxeG + GXEG_US;                  // 131MB f16 E
  unsigned short* wpack  = gxeE + GXEE_US;
  unsigned short* wxpack = wpack + WPACK_US;

  k0_pack<<<1056, 256, 0, stream>>>(gk, ck, wpack, wxpack);
  k1_gxe<<<dim3(16, T_TOTAL), 256, 0, stream>>>(x, nz, gb, cb, wxpack, gxeG, gxeE);
  k2_rec<<<16, 512, 0, stream>>>(h0, wpack, gxeG, gxeE, out);
}